// Round 3
// baseline (205.755 us; speedup 1.0000x reference)
//
#include <hip/hip_runtime.h>

#define N 8
#define L 6400
#define C 256
#define K 100
#define CPS 32              // chunks per (n,half) segment
#define RPC (L / CPS)       // 200 rows per chunk
typedef unsigned long long u64;

// ---- kern1: per-chunk column sums; LAST block combines + argmax ------------
// grid 512. Phase A identical arithmetic/order to R2 kA (absmax 0.0 preserved).
__global__ void __launch_bounds__(256)
kern1(const float* __restrict__ prob, double* __restrict__ P,
      int* __restrict__ kstar, unsigned int* __restrict__ ctr) {
    int b = blockIdx.x;                 // 0..511
    int seg = b >> 5, chunk = b & 31;   // seg = n*2+half
    int t = threadIdx.x;
    int r8 = t >> 5, g = t & 31;
    const float4* base = (const float4*)prob
        + (size_t)seg * (L * 25) + (size_t)chunk * (RPC * 25);
    double a0 = 0, a1 = 0, a2 = 0, a3 = 0;
    if (g < 25) {
#pragma unroll
        for (int i = 0; i < RPC / 8; ++i) {       // 25 iters, independent f4 loads
            float4 v = base[(i * 8 + r8) * 25 + g];
            a0 += v.x; a1 += v.y; a2 += v.z; a3 += v.w;
        }
    }
    __shared__ double sdata[8][100];
    if (g < 25) {
        int k4 = g * 4;
        sdata[r8][k4] = a0; sdata[r8][k4 + 1] = a1;
        sdata[r8][k4 + 2] = a2; sdata[r8][k4 + 3] = a3;
    }
    __syncthreads();
    if (t < 100) {
        double s = 0;
#pragma unroll
        for (int r = 0; r < 8; ++r) s += sdata[r][t];
        P[b * 100 + t] = s;
    }
    // ---- last-block combine + argmax (replaces kB dispatch) ----
    __syncthreads();                      // all P stores drained (vmcnt(0))
    __shared__ unsigned int ord;
    if (t == 0) { __threadfence(); ord = atomicAdd(ctr, 1); }
    __syncthreads();
    if (ord != 511) return;
    __threadfence();                      // acquire: see all blocks' P
    __shared__ double vbuf[8][100];
    if (t < 100) {
        for (int n = 0; n < N; ++n) {
            const double* p0 = P + (size_t)(2 * n) * CPS * 100 + t;
            const double* p1 = P + (size_t)(2 * n + 1) * CPS * 100 + t;
            double s0 = 0, s1 = 0;
#pragma unroll 8
            for (int c = 0; c < CPS; ++c) { s0 += p0[c * 100]; s1 += p1[c * 100]; }
            vbuf[n][t] = s0 * s1;
        }
    }
    __syncthreads();
    if (t < N) {                          // strict '>' -> first-max tie-break
        double best = -1.0; int bi = 0;
        for (int k = 0; k < K; ++k) {
            double v = vbuf[t][k];
            if (v > best) { best = v; bi = k; }
        }
        kstar[t] = bi;
    }
}

// ---- kern2: topic-column ballot bits; LAST block does prefix offsets -------
// grid 200 (n uniform per block since L%256==0).
__global__ void __launch_bounds__(256)
kern2(const float* __restrict__ topics, const int* __restrict__ kstar,
      u64* __restrict__ bits, int* __restrict__ woffs,
      int* __restrict__ lenbuf, unsigned int* __restrict__ ctr) {
    int idx = blockIdx.x * 256 + threadIdx.x;     // < N*L
    int n = idx / L;
    int l = idx - n * L;
    int k = kstar[n];
    float v = topics[((size_t)n * 2 * L + (size_t)l) * K + (size_t)k];
    u64 bal = __ballot(v > 0.5f);
    if ((threadIdx.x & 63) == 0) bits[idx >> 6] = bal;
    __syncthreads();
    __shared__ unsigned int ord;
    if (threadIdx.x == 0) { __threadfence(); ord = atomicAdd(ctr, 1); }
    __syncthreads();
    if (ord != 199) return;
    __threadfence();
    __shared__ int cnts[N * 100];
    int t = threadIdx.x;
    for (int i = t; i < N * 100; i += 256) cnts[i] = __popcll(bits[i]);
    __syncthreads();
    if (t < N) {
        int s = 0;
        int* wo = woffs + t * 100;
        const int* cn = cnts + t * 100;
        for (int w = 0; w < 100; ++w) { wo[w] = s; s += cn[w]; }
        lenbuf[t] = s;
    }
}

// ---- kern3: scatter selected rows + zero-fill + coalesced new_mask ---------
// grid 12800, one wave per row; first 200 blocks also emit the mask.
__global__ void __launch_bounds__(256)
kern3(const float* __restrict__ feat, const u64* __restrict__ bits,
      const int* __restrict__ woffs, const int* __restrict__ lenbuf,
      float* __restrict__ out) {
    int gtid = blockIdx.x * 256 + threadIdx.x;
    if (gtid < N * L) {                   // mask: flat [n][l] == gtid order
        int nm = gtid / L;
        out[(size_t)N * L * C + gtid] = ((gtid - nm * L) < lenbuf[nm]) ? 1.0f : 0.0f;
    }
    int r = blockIdx.x * 4 + (threadIdx.x >> 6);
    int lane = threadIdx.x & 63;
    int n = r / L;
    int l = r - n * L;
    u64 word = bits[r >> 6];
    int len = lenbuf[n];
    const float4* f4 = (const float4*)feat;
    float4* o4 = (float4*)out;
    int bpos = l & 63;
    if ((word >> bpos) & 1ull) {
        int d = woffs[n * 100 + (l >> 6)]
              + __popcll(word & ((1ull << bpos) - 1ull));
        float4 v = f4[(size_t)r * 64 + lane];
        o4[((size_t)n * L + (size_t)d) * 64 + lane] = v;
    }
    if (l >= len)
        o4[(size_t)r * 64 + lane] = make_float4(0.f, 0.f, 0.f, 0.f);
}

extern "C" void kernel_launch(void* const* d_in, const int* in_sizes, int n_in,
                              void* d_out, int out_size, void* d_ws, size_t ws_size,
                              hipStream_t stream) {
    const float* feat   = (const float*)d_in[0];
    const float* prob   = (const float*)d_in[1];
    const float* topics = (const float*)d_in[2];

    // ws layout (poisoned 0xAA each call; every word written before read)
    double* P       = (double*)d_ws;                         // 512*100
    u64*    bits    = (u64*)(P + 512 * 100);                 // 800
    int*    woffs   = (int*)(bits + 800);                    // 800
    int*    kstar   = woffs + 800;                           // 8
    int*    lenbuf  = kstar + 8;                             // 8
    unsigned int* ctrs = (unsigned int*)(lenbuf + 8);        // 2

    float* out = (float*)d_out;

    hipMemsetAsync(ctrs, 0, 2 * sizeof(unsigned int), stream);
    kern1<<<512,  256, 0, stream>>>(prob, P, kstar, ctrs + 0);
    kern2<<<200,  256, 0, stream>>>(topics, kstar, bits, woffs, lenbuf, ctrs + 1);
    kern3<<<12800, 256, 0, stream>>>(feat, bits, woffs, lenbuf, out);
}

// Round 5
// 170.628 us; speedup vs baseline: 1.2059x; 1.2059x over previous
//
#include <hip/hip_runtime.h>

#define N 8
#define L 6400
#define C 256
#define K 100
#define CPS 32              // chunks per (n,half) segment
#define RPC (L / CPS)       // 200 rows per chunk
typedef unsigned long long u64;

// ---- kA: per-chunk column sums -> P[b][k] fp64, b = seg*CPS + chunk --------
// 512 blocks x 640 threads (20 waves/CU). Group g=t&31 (g<25) owns cols
// 4g..4g+3 of row stream rr=t>>5 (20 streams); explicit float4 v[10] batch
// forces all loads in flight before the fp64 adds (chain depth 10).
__global__ void __launch_bounds__(640)
kA_partial(const float* __restrict__ prob, double* __restrict__ P) {
    int b = blockIdx.x;                  // 0..511
    int seg = b >> 5, chunk = b & 31;
    int t = threadIdx.x;
    int rr = t >> 5, g = t & 31;         // rr: 0..19
    const float4* base = (const float4*)prob
        + (size_t)seg * (L * 25) + (size_t)chunk * (RPC * 25);
    double a0 = 0, a1 = 0, a2 = 0, a3 = 0;
    if (g < 25) {
        float4 v[10];
#pragma unroll
        for (int i = 0; i < 10; ++i)
            v[i] = base[(size_t)(i * 20 + rr) * 25 + g];
#pragma unroll
        for (int i = 0; i < 10; ++i) {
            a0 += v[i].x; a1 += v[i].y; a2 += v[i].z; a3 += v[i].w;
        }
    }
    __shared__ double sdata[20][100];
    if (g < 25) {
        int k4 = g * 4;
        sdata[rr][k4] = a0; sdata[rr][k4 + 1] = a1;
        sdata[rr][k4 + 2] = a2; sdata[rr][k4 + 3] = a3;
    }
    __syncthreads();
    if (t < 100) {
        double s = 0;
#pragma unroll
        for (int r = 0; r < 20; ++r) s += sdata[r][t];
        P[b * 100 + t] = s;
    }
}

// ---- kB: per-n combine chunks + argmax (strict '>' = first-max tie-break) --
__global__ void kB_argmax(const double* __restrict__ P, int* __restrict__ kstar) {
    int n = blockIdx.x, t = threadIdx.x;      // 128 threads
    __shared__ double vbuf[100];
    if (t < 100) {
        const double* p0 = P + (size_t)(2 * n) * CPS * 100 + t;
        const double* p1 = P + (size_t)(2 * n + 1) * CPS * 100 + t;
        double s0 = 0, s1 = 0;
#pragma unroll 8
        for (int c = 0; c < CPS; ++c) { s0 += p0[c * 100]; s1 += p1[c * 100]; }
        vbuf[t] = s0 * s1;
    }
    __syncthreads();
    if (t == 0) {
        double best = -1.0; int bi = 0;
        for (int k = 0; k < K; ++k) {
            double v = vbuf[k];
            if (v > best) { best = v; bi = k; }
        }
        kstar[n] = bi;
    }
}

// ---- kC: gather topic column -> ballot bitmask (u64 per 64 rows) -----------
__global__ void kC_bits(const float* __restrict__ topics,
                        const int* __restrict__ kstar,
                        u64* __restrict__ bits) {
    int idx = blockIdx.x * 256 + threadIdx.x;     // < N*L
    int n = idx / L;
    int l = idx - n * L;
    int k = kstar[n];
    float v = topics[((size_t)n * 2 * L + (size_t)l) * K + (size_t)k];
    u64 bal = __ballot(v > 0.5f);
    if ((threadIdx.x & 63) == 0) bits[idx >> 6] = bal;
}

// ---- kD: per-n word-prefix offsets + len (8 parallel blocks) ---------------
__global__ void kD_scan(const u64* __restrict__ bits,
                        int* __restrict__ woffs, int* __restrict__ lenbuf) {
    int n = blockIdx.x, t = threadIdx.x;      // 128 threads
    __shared__ int cnts[100];
    if (t < 100) cnts[t] = __popcll(bits[n * 100 + t]);
    __syncthreads();
    if (t < 100) {
        int s = 0;
        for (int w = 0; w < t; ++w) s += cnts[w];
        woffs[n * 100 + t] = s;
    }
    if (t == 0) {
        int s = 0;
        for (int w = 0; w < 100; ++w) s += cnts[w];
        lenbuf[n] = s;
    }
}

// ---- kE: one wave per row: scatter + zero-fill + coalesced new_mask --------
__global__ void __launch_bounds__(256)
kE_out(const float* __restrict__ feat, const u64* __restrict__ bits,
       const int* __restrict__ woffs, const int* __restrict__ lenbuf,
       float* __restrict__ out) {
    int gtid = blockIdx.x * 256 + threadIdx.x;
    if (gtid < N * L) {                   // new_mask, flat [n][l] == gtid order
        int nm = gtid / L;
        out[(size_t)N * L * C + gtid] = ((gtid - nm * L) < lenbuf[nm]) ? 1.0f : 0.0f;
    }
    int r = blockIdx.x * 4 + (threadIdx.x >> 6);
    int lane = threadIdx.x & 63;
    int n = r / L;
    int l = r - n * L;
    u64 word = bits[r >> 6];
    int len = lenbuf[n];
    const float4* f4 = (const float4*)feat;
    float4* o4 = (float4*)out;
    int bpos = l & 63;
    if ((word >> bpos) & 1ull) {
        int d = woffs[n * 100 + (l >> 6)]
              + __popcll(word & ((1ull << bpos) - 1ull));
        float4 v = f4[(size_t)r * 64 + lane];
        o4[((size_t)n * L + (size_t)d) * 64 + lane] = v;
    }
    if (l >= len)
        o4[(size_t)r * 64 + lane] = make_float4(0.f, 0.f, 0.f, 0.f);
}

extern "C" void kernel_launch(void* const* d_in, const int* in_sizes, int n_in,
                              void* d_out, int out_size, void* d_ws, size_t ws_size,
                              hipStream_t stream) {
    const float* feat   = (const float*)d_in[0];
    const float* prob   = (const float*)d_in[1];
    const float* topics = (const float*)d_in[2];

    // ws layout (~420 KB — same proven footprint as R2)
    double* P       = (double*)d_ws;                    // 512*100 fp64
    u64*    bits    = (u64*)(P + 512 * 100);            // 800
    int*    woffs   = (int*)(bits + 800);               // 800
    int*    kstar   = woffs + 800;                      // 8
    int*    lenbuf  = kstar + 8;                        // 8

    float* out = (float*)d_out;

    kA_partial<<<16 * CPS, 640, 0, stream>>>(prob, P);
    kB_argmax <<<N, 128, 0, stream>>>(P, kstar);
    kC_bits   <<<(N * L) / 256, 256, 0, stream>>>(topics, kstar, bits);
    kD_scan   <<<N, 128, 0, stream>>>(bits, woffs, lenbuf);
    kE_out    <<<(N * L) / 4, 256, 0, stream>>>(feat, bits, woffs, lenbuf, out);
}